// Round 1
// baseline (684.883 us; speedup 1.0000x reference)
//
#include <hip/hip_runtime.h>

// ---------------------------------------------------------------------------
// ImprovedLinkingPredictor: MHA (tiny) + pairwise MLP over 768x768 pairs.
// Layer1 factored: pairs@w1.T = A[i] + att_j @ Weff(i)  (+ spatial terms),
// Weff[d,o] = att_i[d]*W1c[o,d] + W1b[o,d]  built per-workgroup during staging.
// ---------------------------------------------------------------------------

typedef __attribute__((ext_vector_type(8))) __bf16 bf16x8;   // MFMA A/B frag (4 VGPR)
typedef __attribute__((ext_vector_type(4))) float f32x4;     // MFMA C/D frag

__device__ __forceinline__ float bf2f(unsigned short u) {
    return __uint_as_float(((unsigned int)u) << 16);
}
__device__ __forceinline__ unsigned short f2bf(float f) {
    unsigned int x = __float_as_uint(f);
    x += 0x7FFFu + ((x >> 16) & 1u);      // RNE (NaN ignored; none expected)
    return (unsigned short)(x >> 16);
}

// ---------------- weight pre-pack to bf16 ----------------------------------
__global__ __launch_bounds__(256) void pack_weights(
    const float* __restrict__ w1, const float* __restrict__ w2,
    const float* __restrict__ w3, const float* __restrict__ w4,
    unsigned short* __restrict__ w1b_bf, unsigned short* __restrict__ w1c_bf,
    unsigned short* __restrict__ w2_bf, unsigned short* __restrict__ w3_bf,
    unsigned short* __restrict__ w4_bf)
{
    int t = blockIdx.x * 256 + threadIdx.x;
    if (t < 65536) {
        int o = t >> 8, d = t & 255;
        w1b_bf[t] = f2bf(w1[o * 771 + 256 + d]);   // fj block
        w1c_bf[t] = f2bf(w1[o * 771 + 512 + d]);   // fi*fj block
    }
    if (t < 32768) w2_bf[t] = f2bf(w2[t]);
    if (t < 8192)  w3_bf[t] = f2bf(w3[t]);
    if (t < 2048)  w4_bf[t] = f2bf(w4[t]);
}

// ---------------- generic fp32 GEMM: C[M,N] = X[M,K] @ W[N,K]^T + bias -----
__global__ __launch_bounds__(256) void gemm_xwT(
    const float* __restrict__ X, const float* __restrict__ W,
    const float* __restrict__ bias, float* __restrict__ C,
    unsigned short* __restrict__ Cbf, int M, int N, int K, int ldw)
{
    __shared__ float sX[64][33];
    __shared__ float sW[64][33];
    const int tx = threadIdx.x & 15, ty = threadIdx.x >> 4;
    const int bm = blockIdx.x * 64, bn = blockIdx.y * 64;
    float acc[4][4] = {};
    for (int k0 = 0; k0 < K; k0 += 32) {
        for (int t = threadIdx.x; t < 2048; t += 256) {
            int r = t >> 5, c = t & 31;
            sX[r][c] = X[(bm + r) * K + k0 + c];
            sW[r][c] = W[(bn + r) * ldw + k0 + c];
        }
        __syncthreads();
#pragma unroll
        for (int kk = 0; kk < 32; ++kk) {
            float xv[4], wv[4];
#pragma unroll
            for (int a = 0; a < 4; ++a) xv[a] = sX[ty * 4 + a][kk];
#pragma unroll
            for (int b = 0; b < 4; ++b) wv[b] = sW[tx * 4 + b][kk];
#pragma unroll
            for (int a = 0; a < 4; ++a)
#pragma unroll
                for (int b = 0; b < 4; ++b) acc[a][b] += xv[a] * wv[b];
        }
        __syncthreads();
    }
#pragma unroll
    for (int a = 0; a < 4; ++a) {
        int m = bm + ty * 4 + a;
#pragma unroll
        for (int b = 0; b < 4; ++b) {
            int n = bn + tx * 4 + b;
            float v = acc[a][b] + bias[n];
            C[m * N + n] = v;
            if (Cbf) Cbf[m * N + n] = f2bf(v);
        }
    }
}

// ---------------- attention: one block per (query i, head h) ---------------
__global__ __launch_bounds__(256) void attn_k(const float* __restrict__ qkv,
                                              float* __restrict__ O)
{
    __shared__ float sq[32];
    __shared__ float red[256];
    __shared__ float part[256][33];
    const int i = blockIdx.x, h = blockIdx.y, t = threadIdx.x;
    if (t < 32) sq[t] = qkv[i * 768 + h * 32 + t];
    __syncthreads();
    float sc[3];
#pragma unroll
    for (int u = 0; u < 3; ++u) {
        int j = t + u * 256;
        const float* kr = qkv + j * 768 + 256 + h * 32;
        float s = 0.f;
#pragma unroll
        for (int d = 0; d < 32; ++d) s += sq[d] * kr[d];
        sc[u] = s * 0.17677669529663689f;   // 1/sqrt(32)
    }
    float lm = fmaxf(sc[0], fmaxf(sc[1], sc[2]));
    red[t] = lm; __syncthreads();
    for (int s = 128; s > 0; s >>= 1) { if (t < s) red[t] = fmaxf(red[t], red[t + s]); __syncthreads(); }
    float gm = red[0];
    __syncthreads();
    float p[3]; float ls = 0.f;
#pragma unroll
    for (int u = 0; u < 3; ++u) { p[u] = __expf(sc[u] - gm); ls += p[u]; }
    red[t] = ls; __syncthreads();
    for (int s = 128; s > 0; s >>= 1) { if (t < s) red[t] += red[t + s]; __syncthreads(); }
    float inv = 1.0f / red[0];
    float po[32];
#pragma unroll
    for (int d = 0; d < 32; ++d) po[d] = 0.f;
#pragma unroll
    for (int u = 0; u < 3; ++u) {
        int j = t + u * 256;
        const float* vr = qkv + j * 768 + 512 + h * 32;
        float pw = p[u] * inv;
#pragma unroll
        for (int d = 0; d < 32; ++d) po[d] += pw * vr[d];
    }
#pragma unroll
    for (int d = 0; d < 32; ++d) part[t][d] = po[d];
    __syncthreads();
    for (int s = 128; s > 0; s >>= 1) {
        if (t < s)
            for (int d = 0; d < 32; ++d) part[t][d] += part[t + s][d];
        __syncthreads();
    }
    if (t < 32) O[i * 256 + h * 32 + t] = part[0][t];
}

// ---------------- fused pair MLP: 1 i x 128 j per block --------------------
#define STRIDE1 264   // h1 / attj row stride (256 + 8 pad, keeps 16B align)
#define STRIDE2 136   // h2 row stride
#define STRIDE3 72    // h3 row stride

__global__ __launch_bounds__(512, 2) void pair_mlp(
    const float* __restrict__ att, const unsigned short* __restrict__ attb,
    const float* __restrict__ Aarr,
    const unsigned short* __restrict__ w1b_bf, const unsigned short* __restrict__ w1c_bf,
    const float* __restrict__ w1, const float* __restrict__ boxes,
    const float* __restrict__ ln_g, const float* __restrict__ ln_b,
    const unsigned short* __restrict__ w2_bf, const float* __restrict__ b2,
    const unsigned short* __restrict__ w3_bf, const float* __restrict__ b3,
    const unsigned short* __restrict__ w4_bf, const float* __restrict__ b4,
    const float* __restrict__ w5, const float* __restrict__ b5,
    float* __restrict__ out)
{
    __shared__ __align__(16) unsigned short smA[128 * STRIDE1]; // attj -> h1 -> h2 -> h3
    __shared__ __align__(16) unsigned short smB[256 * 72];      // weight staging
    __shared__ float s_w1s[3][256];
    __shared__ float s_lng[256], s_lnb[256];
    __shared__ float s_b2[128], s_b3[64], s_b4[32], s_w5[32];
    __shared__ float s_xd[128], s_ayd[128], s_yd[128];
    __shared__ float s_rsum[128][2], s_rssq[128][2];
    __shared__ float s_l5[128][2];

    const int i    = blockIdx.x;
    const int j0   = blockIdx.y * 128;
    const int tid  = threadIdx.x;
    const int wave = tid >> 6;
    const int lane = tid & 63;
    const int l15  = lane & 15;
    const int quad = lane >> 4;
    const int wr   = wave >> 1;            // 0..3 : row group (32 rows)
    const int wc   = wave & 1;             // 0..1 : col half
    const int arow0 = wr * 32;

    // ---- setup staging ----
    if (tid < 256) {
        s_w1s[0][tid] = w1[tid * 771 + 768];
        s_w1s[1][tid] = w1[tid * 771 + 769];
        s_w1s[2][tid] = w1[tid * 771 + 770];
        s_lng[tid] = ln_g[tid];
        s_lnb[tid] = ln_b[tid];
    } else if (tid < 384) { s_b2[tid - 256] = b2[tid - 256]; }
    else if (tid < 448)   { s_b3[tid - 384] = b3[tid - 384]; }
    else if (tid < 480)   { s_b4[tid - 448] = b4[tid - 448]; }
    else                  { s_w5[tid - 480] = w5[tid - 480]; }
    if (tid < 128) {
        int j = j0 + tid;
        float xd = fabsf(boxes[i * 4 + 0] - boxes[j * 4 + 0]);
        float yd = boxes[i * 4 + 1] - boxes[j * 4 + 1];
        s_xd[tid] = xd; s_yd[tid] = yd; s_ayd[tid] = fabsf(yd);
    }
    // attj tile: 128 rows x 256 bf16
#pragma unroll
    for (int it = 0; it < 8; ++it) {
        int c = tid + it * 512;
        int r = c >> 5, cc = (c & 31) << 3;
        uint4 v = *reinterpret_cast<const uint4*>(&attb[(j0 + r) * 256 + cc]);
        *reinterpret_cast<uint4*>(&smA[r * STRIDE1 + cc]) = v;
    }
    __syncthreads();

    // ======== GEMM1: h1[128 x 256] = attj @ Weff ========
    f32x4 acc[2][8] = {};
    for (int kc = 0; kc < 4; ++kc) {
        const int k0 = kc * 64;
        // stage Weff chunk (256 o x 64 d) -> smB[o][d], stride 72
#pragma unroll
        for (int it = 0; it < 4; ++it) {
            int p = tid + it * 512;
            int o = p >> 3, cc = (p & 7) << 3;
            uint4 vc = *reinterpret_cast<const uint4*>(&w1c_bf[o * 256 + k0 + cc]);
            uint4 vb = *reinterpret_cast<const uint4*>(&w1b_bf[o * 256 + k0 + cc]);
            const unsigned short* pc = reinterpret_cast<const unsigned short*>(&vc);
            const unsigned short* pb = reinterpret_cast<const unsigned short*>(&vb);
            const float4* ap = reinterpret_cast<const float4*>(&att[i * 256 + k0 + cc]);
            float4 A0 = ap[0], A1 = ap[1];
            float ai[8] = {A0.x, A0.y, A0.z, A0.w, A1.x, A1.y, A1.z, A1.w};
            unsigned short op[8];
#pragma unroll
            for (int e = 0; e < 8; ++e)
                op[e] = f2bf(bf2f(pc[e]) * ai[e] + bf2f(pb[e]));
            *reinterpret_cast<uint4*>(&smB[o * 72 + cc]) = *reinterpret_cast<const uint4*>(op);
        }
        __syncthreads();
#pragma unroll
        for (int ks = 0; ks < 2; ++ks) {
            const int kk = k0 + ks * 32;
            bf16x8 a0 = *reinterpret_cast<const bf16x8*>(&smA[(arow0      + l15) * STRIDE1 + kk + quad * 8]);
            bf16x8 a1 = *reinterpret_cast<const bf16x8*>(&smA[(arow0 + 16 + l15) * STRIDE1 + kk + quad * 8]);
#pragma unroll
            for (int ct = 0; ct < 8; ++ct) {
                int o = wc * 128 + ct * 16 + l15;
                bf16x8 bfr = *reinterpret_cast<const bf16x8*>(&smB[o * 72 + ks * 32 + quad * 8]);
                acc[0][ct] = __builtin_amdgcn_mfma_f32_16x16x32_bf16(a0, bfr, acc[0][ct], 0, 0, 0);
                acc[1][ct] = __builtin_amdgcn_mfma_f32_16x16x32_bf16(a1, bfr, acc[1][ct], 0, 0, 0);
            }
        }
        __syncthreads();
    }

    // ---- epilogue1: + A[i] + spatial, relu, LayerNorm -> h1 bf16 in smA ----
    float vsum[2][4] = {}, vssq[2][4] = {};
#pragma unroll
    for (int rt = 0; rt < 2; ++rt)
#pragma unroll
        for (int ct = 0; ct < 8; ++ct) {
            int o = wc * 128 + ct * 16 + l15;
            float Ab = Aarr[i * 256 + o];                 // includes b1
            float w0 = s_w1s[0][o], wv1 = s_w1s[1][o], wv2 = s_w1s[2][o];
#pragma unroll
            for (int r = 0; r < 4; ++r) {
                int m = arow0 + rt * 16 + quad * 4 + r;
                float v = acc[rt][ct][r] + Ab + s_xd[m] * w0 + s_ayd[m] * wv1 + s_yd[m] * wv2;
                v = fmaxf(v, 0.f);
                acc[rt][ct][r] = v;
                vsum[rt][r] += v; vssq[rt][r] += v * v;
            }
        }
#pragma unroll
    for (int mask = 1; mask < 16; mask <<= 1)
#pragma unroll
        for (int rt = 0; rt < 2; ++rt)
#pragma unroll
            for (int r = 0; r < 4; ++r) {
                vsum[rt][r] += __shfl_xor(vsum[rt][r], mask, 64);
                vssq[rt][r] += __shfl_xor(vssq[rt][r], mask, 64);
            }
    if (l15 == 0)
#pragma unroll
        for (int rt = 0; rt < 2; ++rt)
#pragma unroll
            for (int r = 0; r < 4; ++r) {
                int m = arow0 + rt * 16 + quad * 4 + r;
                s_rsum[m][wc] = vsum[rt][r];
                s_rssq[m][wc] = vssq[rt][r];
            }
    __syncthreads();
#pragma unroll
    for (int rt = 0; rt < 2; ++rt) {
        float mu[4], rs[4];
#pragma unroll
        for (int r = 0; r < 4; ++r) {
            int m = arow0 + rt * 16 + quad * 4 + r;
            float sm = (s_rsum[m][0] + s_rsum[m][1]) * (1.0f / 256.0f);
            float sq = (s_rssq[m][0] + s_rssq[m][1]) * (1.0f / 256.0f);
            mu[r] = sm; rs[r] = rsqrtf(sq - sm * sm + 1e-5f);
        }
#pragma unroll
        for (int ct = 0; ct < 8; ++ct) {
            int o = wc * 128 + ct * 16 + l15;
            float g = s_lng[o], bb = s_lnb[o];
#pragma unroll
            for (int r = 0; r < 4; ++r) {
                int m = arow0 + rt * 16 + quad * 4 + r;
                smA[m * STRIDE1 + o] = f2bf((acc[rt][ct][r] - mu[r]) * rs[r] * g + bb);
            }
        }
    }

    // ======== GEMM2: h2[128 x 128] = h1 @ w2^T, relu ========
    f32x4 acc2[2][4] = {};
    for (int kc = 0; kc < 4; ++kc) {
        const int k0 = kc * 64;
#pragma unroll
        for (int it = 0; it < 2; ++it) {
            int p = tid + it * 512;
            int o = p >> 3, cc = (p & 7) << 3;
            *reinterpret_cast<uint4*>(&smB[o * 72 + cc]) =
                *reinterpret_cast<const uint4*>(&w2_bf[o * 256 + k0 + cc]);
        }
        __syncthreads();
#pragma unroll
        for (int ks = 0; ks < 2; ++ks) {
            const int kk = k0 + ks * 32;
            bf16x8 a0 = *reinterpret_cast<const bf16x8*>(&smA[(arow0      + l15) * STRIDE1 + kk + quad * 8]);
            bf16x8 a1 = *reinterpret_cast<const bf16x8*>(&smA[(arow0 + 16 + l15) * STRIDE1 + kk + quad * 8]);
#pragma unroll
            for (int ct = 0; ct < 4; ++ct) {
                int o = wc * 64 + ct * 16 + l15;
                bf16x8 bfr = *reinterpret_cast<const bf16x8*>(&smB[o * 72 + ks * 32 + quad * 8]);
                acc2[0][ct] = __builtin_amdgcn_mfma_f32_16x16x32_bf16(a0, bfr, acc2[0][ct], 0, 0, 0);
                acc2[1][ct] = __builtin_amdgcn_mfma_f32_16x16x32_bf16(a1, bfr, acc2[1][ct], 0, 0, 0);
            }
        }
        __syncthreads();
    }
#pragma unroll
    for (int rt = 0; rt < 2; ++rt)
#pragma unroll
        for (int ct = 0; ct < 4; ++ct) {
            int o = wc * 64 + ct * 16 + l15;
            float bb = s_b2[o];
#pragma unroll
            for (int r = 0; r < 4; ++r) {
                int m = arow0 + rt * 16 + quad * 4 + r;
                smA[m * STRIDE2 + o] = f2bf(fmaxf(acc2[rt][ct][r] + bb, 0.f));
            }
        }
    // stage whole w3 (64 x 128) -> smB stride 136
#pragma unroll
    for (int it = 0; it < 2; ++it) {
        int p = tid + it * 512;
        int o = p >> 4, cc = (p & 15) << 3;
        *reinterpret_cast<uint4*>(&smB[o * 136 + cc]) =
            *reinterpret_cast<const uint4*>(&w3_bf[o * 128 + cc]);
    }
    __syncthreads();

    // ======== GEMM3: h3[128 x 64] = h2 @ w3^T, relu ========
    f32x4 acc3[2][2] = {};
#pragma unroll
    for (int kc = 0; kc < 4; ++kc) {
        const int kk = kc * 32;
        bf16x8 a0 = *reinterpret_cast<const bf16x8*>(&smA[(arow0      + l15) * STRIDE2 + kk + quad * 8]);
        bf16x8 a1 = *reinterpret_cast<const bf16x8*>(&smA[(arow0 + 16 + l15) * STRIDE2 + kk + quad * 8]);
#pragma unroll
        for (int ct = 0; ct < 2; ++ct) {
            int o = wc * 32 + ct * 16 + l15;
            bf16x8 bfr = *reinterpret_cast<const bf16x8*>(&smB[o * 136 + kk + quad * 8]);
            acc3[0][ct] = __builtin_amdgcn_mfma_f32_16x16x32_bf16(a0, bfr, acc3[0][ct], 0, 0, 0);
            acc3[1][ct] = __builtin_amdgcn_mfma_f32_16x16x32_bf16(a1, bfr, acc3[1][ct], 0, 0, 0);
        }
    }
    __syncthreads();
#pragma unroll
    for (int rt = 0; rt < 2; ++rt)
#pragma unroll
        for (int ct = 0; ct < 2; ++ct) {
            int o = wc * 32 + ct * 16 + l15;
            float bb = s_b3[o];
#pragma unroll
            for (int r = 0; r < 4; ++r) {
                int m = arow0 + rt * 16 + quad * 4 + r;
                smA[m * STRIDE3 + o] = f2bf(fmaxf(acc3[rt][ct][r] + bb, 0.f));
            }
        }
    if (tid < 256) {   // stage w4 (32 x 64) -> smB stride 72
        int o = tid >> 3, cc = (tid & 7) << 3;
        *reinterpret_cast<uint4*>(&smB[o * 72 + cc]) =
            *reinterpret_cast<const uint4*>(&w4_bf[o * 64 + cc]);
    }
    __syncthreads();

    // ======== GEMM4: h4[128 x 32] = h3 @ w4^T; relu; layer5 dot ========
    f32x4 acc4[2] = {};
#pragma unroll
    for (int kc = 0; kc < 2; ++kc) {
        const int kk = kc * 32;
        bf16x8 a0 = *reinterpret_cast<const bf16x8*>(&smA[(arow0      + l15) * STRIDE3 + kk + quad * 8]);
        bf16x8 a1 = *reinterpret_cast<const bf16x8*>(&smA[(arow0 + 16 + l15) * STRIDE3 + kk + quad * 8]);
        int o = wc * 16 + l15;
        bf16x8 bfr = *reinterpret_cast<const bf16x8*>(&smB[o * 72 + kk + quad * 8]);
        acc4[0] = __builtin_amdgcn_mfma_f32_16x16x32_bf16(a0, bfr, acc4[0], 0, 0, 0);
        acc4[1] = __builtin_amdgcn_mfma_f32_16x16x32_bf16(a1, bfr, acc4[1], 0, 0, 0);
    }
    float part[2][4];
#pragma unroll
    for (int rt = 0; rt < 2; ++rt) {
        int o = wc * 16 + l15;
        float bb = s_b4[o], wv = s_w5[o];
#pragma unroll
        for (int r = 0; r < 4; ++r)
            part[rt][r] = fmaxf(acc4[rt][r] + bb, 0.f) * wv;
    }
#pragma unroll
    for (int mask = 1; mask < 16; mask <<= 1)
#pragma unroll
        for (int rt = 0; rt < 2; ++rt)
#pragma unroll
            for (int r = 0; r < 4; ++r)
                part[rt][r] += __shfl_xor(part[rt][r], mask, 64);
    if (l15 == 0)
#pragma unroll
        for (int rt = 0; rt < 2; ++rt)
#pragma unroll
            for (int r = 0; r < 4; ++r) {
                int m = arow0 + rt * 16 + quad * 4 + r;
                s_l5[m][wc] = part[rt][r];
            }
    __syncthreads();
    if (tid < 128) {
        int j = j0 + tid;
        float v = s_l5[tid][0] + s_l5[tid][1] + b5[0];
        out[i * 768 + j] = (j == i) ? -1.0e9f : v;
    }
}

// ---------------------------------------------------------------------------
extern "C" void kernel_launch(void* const* d_in, const int* in_sizes, int n_in,
                              void* d_out, int out_size, void* d_ws, size_t ws_size,
                              hipStream_t stream)
{
    const float* features   = (const float*)d_in[0];
    const float* boxes      = (const float*)d_in[1];
    const float* in_proj_w  = (const float*)d_in[2];
    const float* in_proj_b  = (const float*)d_in[3];
    const float* out_proj_w = (const float*)d_in[4];
    const float* out_proj_b = (const float*)d_in[5];
    const float* w1  = (const float*)d_in[6];
    const float* b1  = (const float*)d_in[7];
    const float* ln_g = (const float*)d_in[8];
    const float* ln_b = (const float*)d_in[9];
    const float* w2  = (const float*)d_in[10];
    const float* b2  = (const float*)d_in[11];
    const float* w3  = (const float*)d_in[12];
    const float* b3  = (const float*)d_in[13];
    const float* w4  = (const float*)d_in[14];
    const float* b4  = (const float*)d_in[15];
    const float* w5  = (const float*)d_in[16];
    const float* b5  = (const float*)d_in[17];
    float* out = (float*)d_out;

    // workspace layout
    float* qkv  = (float*)d_ws;            // 768*768
    float* O    = qkv + 589824;            // 768*256
    float* att  = O + 196608;              // 768*256
    float* Aarr = att + 196608;            // 768*256 (att@W1a^T + b1)
    unsigned short* attb   = (unsigned short*)(Aarr + 196608);  // 768*256 bf16
    unsigned short* w1b_bf = attb + 196608;    // 256*256
    unsigned short* w1c_bf = w1b_bf + 65536;   // 256*256
    unsigned short* w2_bf  = w1c_bf + 65536;   // 128*256
    unsigned short* w3_bf  = w2_bf + 32768;    // 64*128
    unsigned short* w4_bf  = w3_bf + 8192;     // 32*64

    pack_weights<<<dim3(256), dim3(256), 0, stream>>>(w1, w2, w3, w4,
        w1b_bf, w1c_bf, w2_bf, w3_bf, w4_bf);
    // qkv = features @ in_proj_w^T + b
    gemm_xwT<<<dim3(12, 12), dim3(256), 0, stream>>>(features, in_proj_w, in_proj_b,
        qkv, (unsigned short*)nullptr, 768, 768, 256, 256);
    attn_k<<<dim3(768, 8), dim3(256), 0, stream>>>(qkv, O);
    // att = O @ out_proj_w^T + b (also bf16 copy)
    gemm_xwT<<<dim3(12, 4), dim3(256), 0, stream>>>(O, out_proj_w, out_proj_b,
        att, attb, 768, 256, 256, 256);
    // Aarr = att @ W1a^T + b1
    gemm_xwT<<<dim3(12, 4), dim3(256), 0, stream>>>(att, w1, b1,
        Aarr, (unsigned short*)nullptr, 768, 256, 256, 771);
    pair_mlp<<<dim3(768, 6), dim3(512), 0, stream>>>(att, attb, Aarr,
        w1b_bf, w1c_bf, w1, boxes, ln_g, ln_b, w2_bf, b2, w3_bf, b3,
        w4_bf, b4, w5, b5, out);
}

// Round 2
// 425.362 us; speedup vs baseline: 1.6101x; 1.6101x over previous
//
#include <hip/hip_runtime.h>

// ---------------------------------------------------------------------------
// ImprovedLinkingPredictor round 2.
// h1[i,j,:] = (att_i .* att_j) @ W1c^T  +  A[i,:]  +  B[j,:]  + spatial@W1s^T
//   A = att @ W1a^T + b1,  B = att @ W1b^T   (one fused 768x512 GEMM)
// pair_mlp: barrier-free K-loops, B-fragments loaded straight from global in
// fragment-major pre-packed layout; LDS holds only the activation tile.
// ---------------------------------------------------------------------------

typedef __attribute__((ext_vector_type(8))) __bf16 bf16x8;   // MFMA A/B frag
typedef __attribute__((ext_vector_type(4))) float f32x4;     // MFMA C/D frag

__device__ __forceinline__ float bf2f(unsigned short u) {
    return __uint_as_float(((unsigned int)u) << 16);
}
__device__ __forceinline__ unsigned short f2bf(float f) {
    unsigned int x = __float_as_uint(f);
    x += 0x7FFFu + ((x >> 16) & 1u);
    return (unsigned short)(x >> 16);
}

// ---------------- pack: bf16 casts + fragment-major weight layouts ----------
// frag-major: elem (o,k) of W[N][K] stored at ((kc*CT + (o>>4))*64 + quad*16
// + l15)*8 + e  with kc=k>>5, quad=(k>>3)&3, e=k&7, l15=o&15  ->  a wave's
// 64 lanes read one contiguous 1KB line per B-fragment.
__global__ __launch_bounds__(256) void pack_all(
    const float* __restrict__ features, const float* __restrict__ in_proj_w,
    const float* __restrict__ out_proj_w, const float* __restrict__ w1,
    const float* __restrict__ w2, const float* __restrict__ w3,
    const float* __restrict__ w4, const float* __restrict__ b1,
    unsigned short* __restrict__ featb, unsigned short* __restrict__ inWb,
    unsigned short* __restrict__ outWb, unsigned short* __restrict__ wABb,
    unsigned short* __restrict__ w1c_f, unsigned short* __restrict__ w2_f,
    unsigned short* __restrict__ w3_f, unsigned short* __restrict__ w4_f,
    float* __restrict__ biasAB, float* __restrict__ w1s_p)
{
    int t = blockIdx.x * 256 + threadIdx.x;
    if (t < 196608) {                         // featb
        featb[t] = f2bf(features[t]);
    } else if (t < 393216) {                  // inWb
        int u = t - 196608; inWb[u] = f2bf(in_proj_w[u]);
    } else if (t < 458752) {                  // outWb
        int u = t - 393216; outWb[u] = f2bf(out_proj_w[u]);
    } else if (t < 589824) {                  // wABb = [w1a ; w1b] rows
        int u = t - 458752; int n = u >> 8, k = u & 255;
        float v = (n < 256) ? w1[n * 771 + k] : w1[(n - 256) * 771 + 256 + k];
        wABb[u] = f2bf(v);
    } else if (t < 655360) {                  // w1c_f (frag-major, K=256,N=256)
        int u = t - 589824;
        int e = u & 7, lane = (u >> 3) & 63, f = u >> 9;
        int l15 = lane & 15, quad = lane >> 4;
        int ct = f & 15, kc = f >> 4;
        int o = ct * 16 + l15, k = kc * 32 + quad * 8 + e;
        w1c_f[u] = f2bf(w1[o * 771 + 512 + k]);
    } else if (t < 688128) {                  // w2_f (K=256,N=128)
        int u = t - 655360;
        int e = u & 7, lane = (u >> 3) & 63, f = u >> 9;
        int l15 = lane & 15, quad = lane >> 4;
        int ct = f & 7, kc = f >> 3;
        int o = ct * 16 + l15, k = kc * 32 + quad * 8 + e;
        w2_f[u] = f2bf(w2[o * 256 + k]);
    } else if (t < 696320) {                  // w3_f (K=128,N=64)
        int u = t - 688128;
        int e = u & 7, lane = (u >> 3) & 63, f = u >> 9;
        int l15 = lane & 15, quad = lane >> 4;
        int ct = f & 3, kc = f >> 2;
        int o = ct * 16 + l15, k = kc * 32 + quad * 8 + e;
        w3_f[u] = f2bf(w3[o * 128 + k]);
    } else if (t < 698368) {                  // w4_f (K=64,N=32)
        int u = t - 696320;
        int e = u & 7, lane = (u >> 3) & 63, f = u >> 9;
        int l15 = lane & 15, quad = lane >> 4;
        int ct = f & 1, kc = f >> 1;
        int o = ct * 16 + l15, k = kc * 32 + quad * 8 + e;
        w4_f[u] = f2bf(w4[o * 64 + k]);
    } else if (t < 698880) {                  // biasAB
        int u = t - 698368;
        biasAB[u] = (u < 256) ? b1[u] : 0.0f;
    } else if (t < 699648) {                  // w1s_p[s*256+o] spatial weights
        int u = t - 698880;
        int s = u >> 8, o = u & 255;
        w1s_p[u] = w1[o * 771 + 768 + s];
    }
}

// ---------------- bf16 MFMA GEMM: C[M,N] = A[M,K] @ W[N,K]^T + bias --------
__global__ __launch_bounds__(256) void gemm_bf(
    const unsigned short* __restrict__ A, const unsigned short* __restrict__ W,
    const float* __restrict__ bias, float* __restrict__ Cf,
    unsigned short* __restrict__ Cbf, int N, int K)
{
    const int wv = threadIdx.x >> 6, lane = threadIdx.x & 63;
    const int l15 = lane & 15, quad = lane >> 4;
    const int row0 = blockIdx.x * 64 + wv * 16;
    const int col0 = blockIdx.y * 64;
    f32x4 acc[4] = {};
    for (int kc = 0; kc < (K >> 5); ++kc) {
        bf16x8 a = *reinterpret_cast<const bf16x8*>(&A[(row0 + l15) * K + kc * 32 + quad * 8]);
#pragma unroll
        for (int ct = 0; ct < 4; ++ct) {
            bf16x8 b = *reinterpret_cast<const bf16x8*>(&W[(col0 + ct * 16 + l15) * K + kc * 32 + quad * 8]);
            acc[ct] = __builtin_amdgcn_mfma_f32_16x16x32_bf16(a, b, acc[ct], 0, 0, 0);
        }
    }
#pragma unroll
    for (int ct = 0; ct < 4; ++ct)
#pragma unroll
        for (int r = 0; r < 4; ++r) {
            int row = row0 + quad * 4 + r, col = col0 + ct * 16 + l15;
            float v = acc[ct][r] + bias[col];
            if (Cf)  Cf[row * N + col] = v;
            if (Cbf) Cbf[row * N + col] = f2bf(v);
        }
}

// ---------------- attention: one block per query i -------------------------
__global__ __launch_bounds__(256) void attn_v2(const unsigned short* __restrict__ qkvb,
                                               unsigned short* __restrict__ Obf)
{
    __shared__ float sq[256];
    __shared__ float sp[768];
    __shared__ float sred[8];
    __shared__ float spv[8][33];
    const int i = blockIdx.x, t = threadIdx.x;
    const int wv = t >> 6, ln = t & 63;
    sq[t] = bf2f(qkvb[i * 768 + t]);
    __syncthreads();
    for (int h = 0; h < 8; ++h) {
        const int hb = h * 32;
        float sc[3];
#pragma unroll
        for (int u = 0; u < 3; ++u) {
            int j = u * 256 + t;
            const unsigned short* kp = qkvb + j * 768 + 256 + hb;
            float s = 0.f;
#pragma unroll
            for (int c = 0; c < 4; ++c) {
                uint4 v = *reinterpret_cast<const uint4*>(&kp[c * 8]);
                const unsigned short* pe = reinterpret_cast<const unsigned short*>(&v);
#pragma unroll
                for (int e = 0; e < 8; ++e) s += sq[hb + c * 8 + e] * bf2f(pe[e]);
            }
            sc[u] = s * 0.17677669529663689f;
        }
        float mx = fmaxf(sc[0], fmaxf(sc[1], sc[2]));
#pragma unroll
        for (int m = 1; m < 64; m <<= 1) mx = fmaxf(mx, __shfl_xor(mx, m, 64));
        if (ln == 0) sred[wv] = mx;
        __syncthreads();
        float gm = fmaxf(fmaxf(sred[0], sred[1]), fmaxf(sred[2], sred[3]));
        float p[3], ls = 0.f;
#pragma unroll
        for (int u = 0; u < 3; ++u) { p[u] = __expf(sc[u] - gm); ls += p[u]; }
#pragma unroll
        for (int m = 1; m < 64; m <<= 1) ls += __shfl_xor(ls, m, 64);
        if (ln == 0) sred[4 + wv] = ls;
        __syncthreads();
        float inv = 1.0f / (sred[4] + sred[5] + sred[6] + sred[7]);
#pragma unroll
        for (int u = 0; u < 3; ++u) sp[u * 256 + t] = p[u] * inv;
        __syncthreads();
        const int g = t >> 5, d = t & 31;
        float a = 0.f;
        const unsigned short* vp = qkvb + 512 + hb + d;
        for (int jj = 0; jj < 96; ++jj)
            a += sp[g * 96 + jj] * bf2f(vp[(g * 96 + jj) * 768]);
        spv[g][d] = a;
        __syncthreads();
        if (t < 32) {
            float s = 0.f;
#pragma unroll
            for (int gg = 0; gg < 8; ++gg) s += spv[gg][t];
            Obf[i * 256 + hb + t] = f2bf(s);
        }
        __syncthreads();
    }
}

// ---------------- fused pair MLP: 1 i x 128 j, barrier-free K-loops --------
#define S1 264
#define S2 136
#define S3 72

__global__ __launch_bounds__(512, 4) void pair_mlp(
    const float* __restrict__ att, const unsigned short* __restrict__ attb,
    const float* __restrict__ AB,
    const unsigned short* __restrict__ w1c_f, const unsigned short* __restrict__ w2_f,
    const unsigned short* __restrict__ w3_f, const unsigned short* __restrict__ w4_f,
    const float* __restrict__ w1s_p, const float* __restrict__ boxes,
    const float* __restrict__ ln_g, const float* __restrict__ ln_b,
    const float* __restrict__ b2, const float* __restrict__ b3,
    const float* __restrict__ b4, const float* __restrict__ w5,
    const float* __restrict__ b5, float* __restrict__ out)
{
    __shared__ __align__(16) unsigned short smA[128 * S1];   // 67.6 KB
    __shared__ float s_xd[128], s_ayd[128], s_yd[128];
    __shared__ float s_rsum[128][2], s_rssq[128][2];
    __shared__ float s_l5[128][2];

    const int i    = blockIdx.x;
    const int j0   = blockIdx.y * 128;
    const int tid  = threadIdx.x;
    const int wave = tid >> 6;
    const int lane = tid & 63;
    const int l15  = lane & 15;
    const int quad = lane >> 4;
    const int wr   = wave >> 1;
    const int wc   = wave & 1;
    const int arow0 = wr * 32;

    if (tid < 128) {
        int j = j0 + tid;
        float xd = fabsf(boxes[i * 4 + 0] - boxes[j * 4 + 0]);
        float yd = boxes[i * 4 + 1] - boxes[j * 4 + 1];
        s_xd[tid] = xd; s_yd[tid] = yd; s_ayd[tid] = fabsf(yd);
    }
    // scaled A-tile: smA[j_local][d] = bf16(att_j[d] * att_i[d])
#pragma unroll
    for (int it = 0; it < 8; ++it) {
        int c = tid + it * 512;
        int r = c >> 5, cc = (c & 31) << 3;
        uint4 v = *reinterpret_cast<const uint4*>(&attb[(j0 + r) * 256 + cc]);
        const unsigned short* pj = reinterpret_cast<const unsigned short*>(&v);
        float4 A0 = *reinterpret_cast<const float4*>(&att[i * 256 + cc]);
        float4 A1 = *reinterpret_cast<const float4*>(&att[i * 256 + cc + 4]);
        float ai[8] = {A0.x, A0.y, A0.z, A0.w, A1.x, A1.y, A1.z, A1.w};
        unsigned short o8[8];
#pragma unroll
        for (int e = 0; e < 8; ++e) o8[e] = f2bf(bf2f(pj[e]) * ai[e]);
        *reinterpret_cast<uint4*>(&smA[r * S1 + cc]) = *reinterpret_cast<const uint4*>(o8);
    }
    __syncthreads();

    // ======== GEMM1 (barrier-free): cross = scaledA @ w1c^T ========
    f32x4 acc[2][8] = {};
    for (int kc = 0; kc < 8; ++kc) {
        bf16x8 a0 = *reinterpret_cast<const bf16x8*>(&smA[(arow0      + l15) * S1 + kc * 32 + quad * 8]);
        bf16x8 a1 = *reinterpret_cast<const bf16x8*>(&smA[(arow0 + 16 + l15) * S1 + kc * 32 + quad * 8]);
#pragma unroll
        for (int ct = 0; ct < 8; ++ct) {
            bf16x8 b = *reinterpret_cast<const bf16x8*>(&w1c_f[((kc * 16 + wc * 8 + ct) * 64 + lane) * 8]);
            acc[0][ct] = __builtin_amdgcn_mfma_f32_16x16x32_bf16(a0, b, acc[0][ct], 0, 0, 0);
            acc[1][ct] = __builtin_amdgcn_mfma_f32_16x16x32_bf16(a1, b, acc[1][ct], 0, 0, 0);
        }
    }

    // ---- epilogue1: + A[i] + B[j] + spatial, relu, LayerNorm ----
    float vsum[2][4] = {}, vssq[2][4] = {};
#pragma unroll
    for (int ct = 0; ct < 8; ++ct) {
        int o = wc * 128 + ct * 16 + l15;
        float Ai = AB[i * 512 + o];
        float w0 = w1s_p[o], wv1 = w1s_p[256 + o], wv2 = w1s_p[512 + o];
#pragma unroll
        for (int rt = 0; rt < 2; ++rt)
#pragma unroll
            for (int r = 0; r < 4; ++r) {
                int m = arow0 + rt * 16 + quad * 4 + r;
                float v = acc[rt][ct][r] + Ai + AB[(j0 + m) * 512 + 256 + o]
                        + s_xd[m] * w0 + s_ayd[m] * wv1 + s_yd[m] * wv2;
                v = fmaxf(v, 0.f);
                acc[rt][ct][r] = v;
                vsum[rt][r] += v; vssq[rt][r] += v * v;
            }
    }
#pragma unroll
    for (int mask = 1; mask < 16; mask <<= 1)
#pragma unroll
        for (int rt = 0; rt < 2; ++rt)
#pragma unroll
            for (int r = 0; r < 4; ++r) {
                vsum[rt][r] += __shfl_xor(vsum[rt][r], mask, 64);
                vssq[rt][r] += __shfl_xor(vssq[rt][r], mask, 64);
            }
    if (l15 == 0)
#pragma unroll
        for (int rt = 0; rt < 2; ++rt)
#pragma unroll
            for (int r = 0; r < 4; ++r) {
                int m = arow0 + rt * 16 + quad * 4 + r;
                s_rsum[m][wc] = vsum[rt][r];
                s_rssq[m][wc] = vssq[rt][r];
            }
    __syncthreads();   // also: all waves done reading scaledA from smA
#pragma unroll
    for (int rt = 0; rt < 2; ++rt) {
        float mu[4], rs[4];
#pragma unroll
        for (int r = 0; r < 4; ++r) {
            int m = arow0 + rt * 16 + quad * 4 + r;
            float sm = (s_rsum[m][0] + s_rsum[m][1]) * (1.0f / 256.0f);
            float sq = (s_rssq[m][0] + s_rssq[m][1]) * (1.0f / 256.0f);
            mu[r] = sm; rs[r] = rsqrtf(sq - sm * sm + 1e-5f);
        }
#pragma unroll
        for (int ct = 0; ct < 8; ++ct) {
            int o = wc * 128 + ct * 16 + l15;
            float g = ln_g[o], bb = ln_b[o];
#pragma unroll
            for (int r = 0; r < 4; ++r) {
                int m = arow0 + rt * 16 + quad * 4 + r;
                smA[m * S1 + o] = f2bf((acc[rt][ct][r] - mu[r]) * rs[r] * g + bb);
            }
        }
    }
    __syncthreads();

    // ======== GEMM2 (barrier-free): h2 = h1 @ w2^T, relu ========
    f32x4 acc2[2][4] = {};
    for (int kc = 0; kc < 8; ++kc) {
        bf16x8 a0 = *reinterpret_cast<const bf16x8*>(&smA[(arow0      + l15) * S1 + kc * 32 + quad * 8]);
        bf16x8 a1 = *reinterpret_cast<const bf16x8*>(&smA[(arow0 + 16 + l15) * S1 + kc * 32 + quad * 8]);
#pragma unroll
        for (int ct = 0; ct < 4; ++ct) {
            bf16x8 b = *reinterpret_cast<const bf16x8*>(&w2_f[((kc * 8 + wc * 4 + ct) * 64 + lane) * 8]);
            acc2[0][ct] = __builtin_amdgcn_mfma_f32_16x16x32_bf16(a0, b, acc2[0][ct], 0, 0, 0);
            acc2[1][ct] = __builtin_amdgcn_mfma_f32_16x16x32_bf16(a1, b, acc2[1][ct], 0, 0, 0);
        }
    }
    __syncthreads();   // all waves done reading h1
#pragma unroll
    for (int rt = 0; rt < 2; ++rt)
#pragma unroll
        for (int ct = 0; ct < 4; ++ct) {
            int o = wc * 64 + ct * 16 + l15;
            float bb = b2[o];
#pragma unroll
            for (int r = 0; r < 4; ++r) {
                int m = arow0 + rt * 16 + quad * 4 + r;
                smA[m * S2 + o] = f2bf(fmaxf(acc2[rt][ct][r] + bb, 0.f));
            }
        }
    __syncthreads();

    // ======== GEMM3: h3 = h2 @ w3^T, relu ========
    f32x4 acc3[2][2] = {};
    for (int kc = 0; kc < 4; ++kc) {
        bf16x8 a0 = *reinterpret_cast<const bf16x8*>(&smA[(arow0      + l15) * S2 + kc * 32 + quad * 8]);
        bf16x8 a1 = *reinterpret_cast<const bf16x8*>(&smA[(arow0 + 16 + l15) * S2 + kc * 32 + quad * 8]);
#pragma unroll
        for (int ct = 0; ct < 2; ++ct) {
            bf16x8 b = *reinterpret_cast<const bf16x8*>(&w3_f[((kc * 4 + wc * 2 + ct) * 64 + lane) * 8]);
            acc3[0][ct] = __builtin_amdgcn_mfma_f32_16x16x32_bf16(a0, b, acc3[0][ct], 0, 0, 0);
            acc3[1][ct] = __builtin_amdgcn_mfma_f32_16x16x32_bf16(a1, b, acc3[1][ct], 0, 0, 0);
        }
    }
    __syncthreads();
#pragma unroll
    for (int rt = 0; rt < 2; ++rt)
#pragma unroll
        for (int ct = 0; ct < 2; ++ct) {
            int o = wc * 32 + ct * 16 + l15;
            float bb = b3[o];
#pragma unroll
            for (int r = 0; r < 4; ++r) {
                int m = arow0 + rt * 16 + quad * 4 + r;
                smA[m * S3 + o] = f2bf(fmaxf(acc3[rt][ct][r] + bb, 0.f));
            }
        }
    __syncthreads();

    // ======== GEMM4 + head ========
    f32x4 acc4[2] = {};
#pragma unroll
    for (int kc = 0; kc < 2; ++kc) {
        bf16x8 a0 = *reinterpret_cast<const bf16x8*>(&smA[(arow0      + l15) * S3 + kc * 32 + quad * 8]);
        bf16x8 a1 = *reinterpret_cast<const bf16x8*>(&smA[(arow0 + 16 + l15) * S3 + kc * 32 + quad * 8]);
        bf16x8 b = *reinterpret_cast<const bf16x8*>(&w4_f[((kc * 2 + wc) * 64 + lane) * 8]);
        acc4[0] = __builtin_amdgcn_mfma_f32_16x16x32_bf16(a0, b, acc4[0], 0, 0, 0);
        acc4[1] = __builtin_amdgcn_mfma_f32_16x16x32_bf16(a1, b, acc4[1], 0, 0, 0);
    }
    {
        int o = wc * 16 + l15;
        float bb = b4[o], wv = w5[o];
        float part[2][4];
#pragma unroll
        for (int rt = 0; rt < 2; ++rt)
#pragma unroll
            for (int r = 0; r < 4; ++r)
                part[rt][r] = fmaxf(acc4[rt][r] + bb, 0.f) * wv;
#pragma unroll
        for (int mask = 1; mask < 16; mask <<= 1)
#pragma unroll
            for (int rt = 0; rt < 2; ++rt)
#pragma unroll
                for (int r = 0; r < 4; ++r)
                    part[rt][r] += __shfl_xor(part[rt][r], mask, 64);
        if (l15 == 0)
#pragma unroll
            for (int rt = 0; rt < 2; ++rt)
#pragma unroll
                for (int r = 0; r < 4; ++r) {
                    int m = arow0 + rt * 16 + quad * 4 + r;
                    s_l5[m][wc] = part[rt][r];
                }
    }
    __syncthreads();
    if (tid < 128) {
        int j = j0 + tid;
        float v = s_l5[tid][0] + s_l5[tid][1] + b5[0];
        out[i * 768 + j] = (j == i) ? -1.0e9f : v;
    }
}

// ---------------------------------------------------------------------------
extern "C" void kernel_launch(void* const* d_in, const int* in_sizes, int n_in,
                              void* d_out, int out_size, void* d_ws, size_t ws_size,
                              hipStream_t stream)
{
    const float* features   = (const float*)d_in[0];
    const float* boxes      = (const float*)d_in[1];
    const float* in_proj_w  = (const float*)d_in[2];
    const float* in_proj_b  = (const float*)d_in[3];
    const float* out_proj_w = (const float*)d_in[4];
    const float* out_proj_b = (const float*)d_in[5];
    const float* w1  = (const float*)d_in[6];
    const float* b1  = (const float*)d_in[7];
    const float* ln_g = (const float*)d_in[8];
    const float* ln_b = (const float*)d_in[9];
    const float* w2  = (const float*)d_in[10];
    const float* b2  = (const float*)d_in[11];
    const float* w3  = (const float*)d_in[12];
    const float* b3  = (const float*)d_in[13];
    const float* w4  = (const float*)d_in[14];
    const float* b4  = (const float*)d_in[15];
    const float* w5  = (const float*)d_in[16];
    const float* b5  = (const float*)d_in[17];
    float* out = (float*)d_out;

    // ---- workspace layout (16B-aligned chunks) ----
    char* p = (char*)d_ws;
    unsigned short* qkvb = (unsigned short*)p; p += 768 * 768 * 2;   // 1179648
    unsigned short* Obf  = (unsigned short*)p; p += 768 * 256 * 2;
    unsigned short* attb = (unsigned short*)p; p += 768 * 256 * 2;
    float* att  = (float*)p; p += 768 * 256 * 4;
    float* AB   = (float*)p; p += 768 * 512 * 4;
    unsigned short* featb = (unsigned short*)p; p += 196608 * 2;
    unsigned short* inWb  = (unsigned short*)p; p += 196608 * 2;
    unsigned short* outWb = (unsigned short*)p; p += 65536 * 2;
    unsigned short* wABb  = (unsigned short*)p; p += 131072 * 2;
    unsigned short* w1c_f = (unsigned short*)p; p += 65536 * 2;
    unsigned short* w2_f  = (unsigned short*)p; p += 32768 * 2;
    unsigned short* w3_f  = (unsigned short*)p; p += 8192 * 2;
    unsigned short* w4_f  = (unsigned short*)p; p += 2048 * 2;
    float* biasAB = (float*)p; p += 512 * 4;
    float* w1s_p  = (float*)p; p += 768 * 4;

    pack_all<<<dim3(2733), dim3(256), 0, stream>>>(features, in_proj_w,
        out_proj_w, w1, w2, w3, w4, b1, featb, inWb, outWb, wABb,
        w1c_f, w2_f, w3_f, w4_f, biasAB, w1s_p);
    // qkv (bf16 only)
    gemm_bf<<<dim3(12, 12), dim3(256), 0, stream>>>(featb, inWb, in_proj_b,
        (float*)nullptr, qkvb, 768, 256);
    attn_v2<<<dim3(768), dim3(256), 0, stream>>>(qkvb, Obf);
    // att = O @ out_proj^T + b  (fp32 + bf16)
    gemm_bf<<<dim3(12, 4), dim3(256), 0, stream>>>(Obf, outWb, out_proj_b,
        att, attb, 256, 256);
    // AB = att @ [w1a;w1b]^T + [b1;0]
    gemm_bf<<<dim3(12, 8), dim3(256), 0, stream>>>(attb, wABb, biasAB,
        AB, (unsigned short*)nullptr, 512, 256);
    pair_mlp<<<dim3(768, 6), dim3(512), 0, stream>>>(att, attb, AB,
        w1c_f, w2_f, w3_f, w4_f, w1s_p, boxes, ln_g, ln_b,
        b2, b3, b4, w5, b5, out);
}

// Round 3
// 366.607 us; speedup vs baseline: 1.8682x; 1.1603x over previous
//
#include <hip/hip_runtime.h>

// ---------------------------------------------------------------------------
// ImprovedLinkingPredictor round 3.
// - LN folded into GEMM2 weights (w2g = w2*ln_g, c1/c2 static correction).
// - HW bf16 converts ((__bf16) cast -> v_cvt_pk_bf16_f32).
// - MFMA fused attention (QK^T -> LDS softmax -> PV with pre-transposed V).
// ---------------------------------------------------------------------------

typedef __attribute__((ext_vector_type(8))) __bf16 bf16x8;   // MFMA A/B frag
typedef __attribute__((ext_vector_type(4))) float f32x4;     // MFMA C/D frag

__device__ __forceinline__ float bf2f(unsigned short u) {
    return __uint_as_float(((unsigned int)u) << 16);
}
__device__ __forceinline__ unsigned short f2bf(float f) {
    union { __bf16 b; unsigned short u; } cv;
    cv.b = (__bf16)f;            // v_cvt_pk_bf16_f32 on gfx950, RNE
    return cv.u;
}

// ---------------- pack: bf16 casts + fragment-major weight layouts ----------
__global__ __launch_bounds__(256) void pack_all(
    const float* __restrict__ features, const float* __restrict__ in_proj_w,
    const float* __restrict__ out_proj_w, const float* __restrict__ w1,
    const float* __restrict__ w2, const float* __restrict__ w3,
    const float* __restrict__ w4, const float* __restrict__ b1,
    const float* __restrict__ ln_g, const float* __restrict__ ln_b,
    const float* __restrict__ b2,
    unsigned short* __restrict__ featb, unsigned short* __restrict__ inWb,
    unsigned short* __restrict__ outWb, unsigned short* __restrict__ wABb,
    unsigned short* __restrict__ w1c_f, unsigned short* __restrict__ w2g_f,
    unsigned short* __restrict__ w3_f, unsigned short* __restrict__ w4_f,
    float* __restrict__ biasAB, float* __restrict__ w1s_p,
    float* __restrict__ c1, float* __restrict__ c2)
{
    int t = blockIdx.x * 256 + threadIdx.x;
    if (t < 196608) {
        featb[t] = f2bf(features[t]);
    } else if (t < 393216) {
        int u = t - 196608; inWb[u] = f2bf(in_proj_w[u]);
    } else if (t < 458752) {
        int u = t - 393216; outWb[u] = f2bf(out_proj_w[u]);
    } else if (t < 589824) {                  // wABb = [w1a ; w1b] rows
        int u = t - 458752; int n = u >> 8, k = u & 255;
        float v = (n < 256) ? w1[n * 771 + k] : w1[(n - 256) * 771 + 256 + k];
        wABb[u] = f2bf(v);
    } else if (t < 655360) {                  // w1c_f (frag-major, K=256,N=256)
        int u = t - 589824;
        int e = u & 7, lane = (u >> 3) & 63, f = u >> 9;
        int l15 = lane & 15, quad = lane >> 4;
        int ct = f & 15, kc = f >> 4;
        int o = ct * 16 + l15, k = kc * 32 + quad * 8 + e;
        w1c_f[u] = f2bf(w1[o * 771 + 512 + k]);
    } else if (t < 688128) {                  // w2g_f = (w2 * ln_g) frag-major
        int u = t - 655360;
        int e = u & 7, lane = (u >> 3) & 63, f = u >> 9;
        int l15 = lane & 15, quad = lane >> 4;
        int ct = f & 7, kc = f >> 3;
        int o = ct * 16 + l15, k = kc * 32 + quad * 8 + e;
        w2g_f[u] = f2bf(w2[o * 256 + k] * ln_g[k]);
    } else if (t < 696320) {                  // w3_f (K=128,N=64)
        int u = t - 688128;
        int e = u & 7, lane = (u >> 3) & 63, f = u >> 9;
        int l15 = lane & 15, quad = lane >> 4;
        int ct = f & 3, kc = f >> 2;
        int o = ct * 16 + l15, k = kc * 32 + quad * 8 + e;
        w3_f[u] = f2bf(w3[o * 128 + k]);
    } else if (t < 698368) {                  // w4_f (K=64,N=32)
        int u = t - 696320;
        int e = u & 7, lane = (u >> 3) & 63, f = u >> 9;
        int l15 = lane & 15, quad = lane >> 4;
        int ct = f & 1, kc = f >> 1;
        int o = ct * 16 + l15, k = kc * 32 + quad * 8 + e;
        w4_f[u] = f2bf(w4[o * 64 + k]);
    } else if (t < 698880) {                  // biasAB
        int u = t - 698368;
        biasAB[u] = (u < 256) ? b1[u] : 0.0f;
    } else if (t < 699648) {                  // w1s_p[s*256+o]
        int u = t - 698880;
        int s = u >> 8, o = u & 255;
        w1s_p[u] = w1[o * 771 + 768 + s];
    } else if (t < 699776) {                  // c1/c2 (LN folding constants)
        int p = t - 699648;
        float s2 = 0.f, s1 = 0.f;
        for (int k = 0; k < 256; ++k) {
            float w = w2[p * 256 + k];
            s2 += ln_g[k] * w;
            s1 += ln_b[k] * w;
        }
        c2[p] = s2;
        c1[p] = s1 + b2[p];
    }
}

// ---------------- bf16 MFMA GEMM: C[M,N] = A[M,K] @ W[N,K]^T + bias --------
// If Vt != nullptr, columns >= 512 are written transposed into Vt (bf16).
__global__ __launch_bounds__(256) void gemm_bf(
    const unsigned short* __restrict__ A, const unsigned short* __restrict__ W,
    const float* __restrict__ bias, float* __restrict__ Cf,
    unsigned short* __restrict__ Cbf, unsigned short* __restrict__ Vt,
    int N, int K)
{
    const int wv = threadIdx.x >> 6, lane = threadIdx.x & 63;
    const int l15 = lane & 15, quad = lane >> 4;
    const int row0 = blockIdx.x * 64 + wv * 16;
    const int col0 = blockIdx.y * 64;
    f32x4 acc[4] = {};
    for (int kc = 0; kc < (K >> 5); ++kc) {
        bf16x8 a = *reinterpret_cast<const bf16x8*>(&A[(row0 + l15) * K + kc * 32 + quad * 8]);
#pragma unroll
        for (int ct = 0; ct < 4; ++ct) {
            bf16x8 b = *reinterpret_cast<const bf16x8*>(&W[(col0 + ct * 16 + l15) * K + kc * 32 + quad * 8]);
            acc[ct] = __builtin_amdgcn_mfma_f32_16x16x32_bf16(a, b, acc[ct], 0, 0, 0);
        }
    }
#pragma unroll
    for (int ct = 0; ct < 4; ++ct)
#pragma unroll
        for (int r = 0; r < 4; ++r) {
            int row = row0 + quad * 4 + r, col = col0 + ct * 16 + l15;
            float v = acc[ct][r] + bias[col];
            if (Vt && col >= 512) {
                Vt[(col - 512) * 768 + row] = f2bf(v);
            } else {
                if (Cf)  Cf[row * N + col] = v;
                if (Cbf) Cbf[row * N + col] = f2bf(v);
            }
        }
}

// ---------------- fused MFMA attention -------------------------------------
// block = (head h, 64 q-rows). QK^T -> smS (bf16, scaled), softmax in-place,
// PV from smS (A) x Vt (B, global). Obf[q,256] written bf16.
#define SP 776   // 768 + 8 shorts pad

__global__ __launch_bounds__(256) void attn_mfma(
    const unsigned short* __restrict__ qkvb, const unsigned short* __restrict__ Vt,
    unsigned short* __restrict__ Obf)
{
    __shared__ __align__(16) unsigned short smS[64 * SP];   // 99.3 KB
    const int h = blockIdx.x, q0 = blockIdx.y * 64, hb = h * 32;
    const int tid = threadIdx.x, wave = tid >> 6, lane = tid & 63;
    const int l15 = lane & 15, quad = lane >> 4;

    // ---- QK^T: wave covers cols [wave*192, +192) x all 64 rows ----
    bf16x8 af[4];
#pragma unroll
    for (int mt = 0; mt < 4; ++mt)
        af[mt] = *reinterpret_cast<const bf16x8*>(&qkvb[(q0 + mt * 16 + l15) * 768 + hb + quad * 8]);
#pragma unroll
    for (int ct = 0; ct < 12; ++ct) {
        int n0 = wave * 192 + ct * 16;
        bf16x8 b = *reinterpret_cast<const bf16x8*>(&qkvb[(n0 + l15) * 768 + 256 + hb + quad * 8]);
#pragma unroll
        for (int mt = 0; mt < 4; ++mt) {
            f32x4 c = {};
            c = __builtin_amdgcn_mfma_f32_16x16x32_bf16(af[mt], b, c, 0, 0, 0);
#pragma unroll
            for (int r = 0; r < 4; ++r)
                smS[(mt * 16 + quad * 4 + r) * SP + n0 + l15] =
                    f2bf(c[r] * 0.17677669529663689f);
        }
    }
    __syncthreads();

    // ---- row softmax: 4 threads per row, 192 cols each ----
    {
        const int row = tid >> 2, part = tid & 3;
        unsigned short* rp = &smS[row * SP + part * 192];
        float mx = -3.0e38f;
#pragma unroll
        for (int c8 = 0; c8 < 24; ++c8) {
            uint4 v = *reinterpret_cast<const uint4*>(&rp[c8 * 8]);
            const unsigned short* pe = reinterpret_cast<const unsigned short*>(&v);
#pragma unroll
            for (int e = 0; e < 8; ++e) mx = fmaxf(mx, bf2f(pe[e]));
        }
        mx = fmaxf(mx, __shfl_xor(mx, 1, 64));
        mx = fmaxf(mx, __shfl_xor(mx, 2, 64));
        float ls = 0.f;
#pragma unroll
        for (int c8 = 0; c8 < 24; ++c8) {
            uint4 v = *reinterpret_cast<const uint4*>(&rp[c8 * 8]);
            const unsigned short* pe = reinterpret_cast<const unsigned short*>(&v);
            unsigned short o8[8];
#pragma unroll
            for (int e = 0; e < 8; ++e) {
                float ev = __expf(bf2f(pe[e]) - mx);
                ls += ev;
                o8[e] = f2bf(ev);
            }
            *reinterpret_cast<uint4*>(&rp[c8 * 8]) = *reinterpret_cast<const uint4*>(o8);
        }
        ls += __shfl_xor(ls, 1, 64);
        ls += __shfl_xor(ls, 2, 64);
        float inv = 1.0f / ls;
#pragma unroll
        for (int c8 = 0; c8 < 24; ++c8) {
            uint4 v = *reinterpret_cast<const uint4*>(&rp[c8 * 8]);
            const unsigned short* pe = reinterpret_cast<const unsigned short*>(&v);
            unsigned short o8[8];
#pragma unroll
            for (int e = 0; e < 8; ++e) o8[e] = f2bf(bf2f(pe[e]) * inv);
            *reinterpret_cast<uint4*>(&rp[c8 * 8]) = *reinterpret_cast<const uint4*>(o8);
        }
    }
    // PV consumes only this wave's own rows (wave*16..+16) -> no barrier needed.

    // ---- PV: 16 rows per wave x 32 cols, K = 768 ----
    f32x4 accp[2] = {};
    for (int kc = 0; kc < 24; ++kc) {
        bf16x8 a = *reinterpret_cast<const bf16x8*>(&smS[(wave * 16 + l15) * SP + kc * 32 + quad * 8]);
#pragma unroll
        for (int ct = 0; ct < 2; ++ct) {
            bf16x8 b = *reinterpret_cast<const bf16x8*>(&Vt[(hb + ct * 16 + l15) * 768 + kc * 32 + quad * 8]);
            accp[ct] = __builtin_amdgcn_mfma_f32_16x16x32_bf16(a, b, accp[ct], 0, 0, 0);
        }
    }
#pragma unroll
    for (int ct = 0; ct < 2; ++ct)
#pragma unroll
        for (int r = 0; r < 4; ++r) {
            int row = q0 + wave * 16 + quad * 4 + r;
            Obf[row * 256 + hb + ct * 16 + l15] = f2bf(accp[ct][r]);
        }
}

// ---------------- fused pair MLP -------------------------------------------
#define S1 264
#define S2 136
#define S3 72

__global__ __launch_bounds__(512, 4) void pair_mlp(
    const float* __restrict__ att, const unsigned short* __restrict__ attb,
    const float* __restrict__ AB,
    const unsigned short* __restrict__ w1c_f, const unsigned short* __restrict__ w2g_f,
    const unsigned short* __restrict__ w3_f, const unsigned short* __restrict__ w4_f,
    const float* __restrict__ w1s_p, const float* __restrict__ boxes,
    const float* __restrict__ c1, const float* __restrict__ c2,
    const float* __restrict__ b3, const float* __restrict__ b4,
    const float* __restrict__ w5, const float* __restrict__ b5,
    float* __restrict__ out)
{
    __shared__ __align__(16) unsigned short smA[128 * S1];   // 67.6 KB
    __shared__ float s_xd[128], s_ayd[128], s_yd[128];
    __shared__ float s_rsum[128][2], s_rssq[128][2];
    __shared__ float s_l5[128][2];

    const int i    = blockIdx.x;
    const int j0   = blockIdx.y * 128;
    const int tid  = threadIdx.x;
    const int wave = tid >> 6;
    const int lane = tid & 63;
    const int l15  = lane & 15;
    const int quad = lane >> 4;
    const int wr   = wave >> 1;
    const int wc   = wave & 1;
    const int arow0 = wr * 32;

    if (tid < 128) {
        int j = j0 + tid;
        float xd = fabsf(boxes[i * 4 + 0] - boxes[j * 4 + 0]);
        float yd = boxes[i * 4 + 1] - boxes[j * 4 + 1];
        s_xd[tid] = xd; s_yd[tid] = yd; s_ayd[tid] = fabsf(yd);
    }
    // scaled A-tile: smA[j_local][d] = bf16(att_j[d] * att_i[d])
#pragma unroll
    for (int it = 0; it < 8; ++it) {
        int c = tid + it * 512;
        int r = c >> 5, cc = (c & 31) << 3;
        uint4 v = *reinterpret_cast<const uint4*>(&attb[(j0 + r) * 256 + cc]);
        const unsigned short* pj = reinterpret_cast<const unsigned short*>(&v);
        float4 A0 = *reinterpret_cast<const float4*>(&att[i * 256 + cc]);
        float4 A1 = *reinterpret_cast<const float4*>(&att[i * 256 + cc + 4]);
        float ai[8] = {A0.x, A0.y, A0.z, A0.w, A1.x, A1.y, A1.z, A1.w};
        unsigned short o8[8];
#pragma unroll
        for (int e = 0; e < 8; ++e) o8[e] = f2bf(bf2f(pj[e]) * ai[e]);
        *reinterpret_cast<uint4*>(&smA[r * S1 + cc]) = *reinterpret_cast<const uint4*>(o8);
    }
    __syncthreads();                                          // B0

    // ======== GEMM1 (barrier-free): cross = scaledA @ w1c^T ========
    f32x4 acc[2][8] = {};
    for (int kc = 0; kc < 8; ++kc) {
        bf16x8 a0 = *reinterpret_cast<const bf16x8*>(&smA[(arow0      + l15) * S1 + kc * 32 + quad * 8]);
        bf16x8 a1 = *reinterpret_cast<const bf16x8*>(&smA[(arow0 + 16 + l15) * S1 + kc * 32 + quad * 8]);
#pragma unroll
        for (int ct = 0; ct < 8; ++ct) {
            bf16x8 b = *reinterpret_cast<const bf16x8*>(&w1c_f[((kc * 16 + wc * 8 + ct) * 64 + lane) * 8]);
            acc[0][ct] = __builtin_amdgcn_mfma_f32_16x16x32_bf16(a0, b, acc[0][ct], 0, 0, 0);
            acc[1][ct] = __builtin_amdgcn_mfma_f32_16x16x32_bf16(a1, b, acc[1][ct], 0, 0, 0);
        }
    }

    // ---- epilogue1 (pre-barrier): + A[i] + B[j] + spatial, relu, stats ----
    float vsum[2][4] = {}, vssq[2][4] = {};
#pragma unroll
    for (int ct = 0; ct < 8; ++ct) {
        int o = wc * 128 + ct * 16 + l15;
        float Ai = AB[i * 512 + o];
        float w0 = w1s_p[o], wv1 = w1s_p[256 + o], wv2 = w1s_p[512 + o];
#pragma unroll
        for (int rt = 0; rt < 2; ++rt)
#pragma unroll
            for (int r = 0; r < 4; ++r) {
                int m = arow0 + rt * 16 + quad * 4 + r;
                float v = acc[rt][ct][r] + Ai + AB[(j0 + m) * 512 + 256 + o]
                        + s_xd[m] * w0 + s_ayd[m] * wv1 + s_yd[m] * wv2;
                v = fmaxf(v, 0.f);
                acc[rt][ct][r] = v;
                vsum[rt][r] += v; vssq[rt][r] += v * v;
            }
    }
#pragma unroll
    for (int mask = 1; mask < 16; mask <<= 1)
#pragma unroll
        for (int rt = 0; rt < 2; ++rt)
#pragma unroll
            for (int r = 0; r < 4; ++r) {
                vsum[rt][r] += __shfl_xor(vsum[rt][r], mask, 64);
                vssq[rt][r] += __shfl_xor(vssq[rt][r], mask, 64);
            }
    if (l15 == 0)
#pragma unroll
        for (int rt = 0; rt < 2; ++rt)
#pragma unroll
            for (int r = 0; r < 4; ++r) {
                int m = arow0 + rt * 16 + quad * 4 + r;
                s_rsum[m][wc] = vsum[rt][r];
                s_rssq[m][wc] = vssq[rt][r];
            }
    __syncthreads();                                          // B1 scaledA done
    // ---- write raw relu'd h1 (bf16) -- LN applied algebraically in GEMM2 ---
#pragma unroll
    for (int ct = 0; ct < 8; ++ct) {
        int o = wc * 128 + ct * 16 + l15;
#pragma unroll
        for (int rt = 0; rt < 2; ++rt)
#pragma unroll
            for (int r = 0; r < 4; ++r) {
                int m = arow0 + rt * 16 + quad * 4 + r;
                smA[m * S1 + o] = f2bf(acc[rt][ct][r]);
            }
    }
    __syncthreads();                                          // B2

    // ======== GEMM2 (barrier-free): S = h1 @ w2g^T ========
    f32x4 acc2[2][4] = {};
    for (int kc = 0; kc < 8; ++kc) {
        bf16x8 a0 = *reinterpret_cast<const bf16x8*>(&smA[(arow0      + l15) * S1 + kc * 32 + quad * 8]);
        bf16x8 a1 = *reinterpret_cast<const bf16x8*>(&smA[(arow0 + 16 + l15) * S1 + kc * 32 + quad * 8]);
#pragma unroll
        for (int ct = 0; ct < 4; ++ct) {
            bf16x8 b = *reinterpret_cast<const bf16x8*>(&w2g_f[((kc * 8 + wc * 4 + ct) * 64 + lane) * 8]);
            acc2[0][ct] = __builtin_amdgcn_mfma_f32_16x16x32_bf16(a0, b, acc2[0][ct], 0, 0, 0);
            acc2[1][ct] = __builtin_amdgcn_mfma_f32_16x16x32_bf16(a1, b, acc2[1][ct], 0, 0, 0);
        }
    }
    // LN stats for this thread's 8 rows
    float mu[2][4], rs[2][4];
#pragma unroll
    for (int rt = 0; rt < 2; ++rt)
#pragma unroll
        for (int r = 0; r < 4; ++r) {
            int m = arow0 + rt * 16 + quad * 4 + r;
            float sm = (s_rsum[m][0] + s_rsum[m][1]) * (1.0f / 256.0f);
            float sq = (s_rssq[m][0] + s_rssq[m][1]) * (1.0f / 256.0f);
            mu[rt][r] = sm;
            rs[rt][r] = rsqrtf(sq - sm * sm + 1e-5f);
        }
    __syncthreads();                                          // B3 h1 reads done
#pragma unroll
    for (int ct = 0; ct < 4; ++ct) {
        int p = wc * 64 + ct * 16 + l15;
        float C1 = c1[p], C2 = c2[p];
#pragma unroll
        for (int rt = 0; rt < 2; ++rt)
#pragma unroll
            for (int r = 0; r < 4; ++r) {
                int m = arow0 + rt * 16 + quad * 4 + r;
                float v = rs[rt][r] * (acc2[rt][ct][r] - mu[rt][r] * C2) + C1;
                smA[m * S2 + p] = f2bf(fmaxf(v, 0.f));
            }
    }
    __syncthreads();                                          // B4

    // ======== GEMM3: h3 = h2 @ w3^T, relu ========
    f32x4 acc3[2][2] = {};
    for (int kc = 0; kc < 4; ++kc) {
        bf16x8 a0 = *reinterpret_cast<const bf16x8*>(&smA[(arow0      + l15) * S2 + kc * 32 + quad * 8]);
        bf16x8 a1 = *reinterpret_cast<const bf16x8*>(&smA[(arow0 + 16 + l15) * S2 + kc * 32 + quad * 8]);
#pragma unroll
        for (int ct = 0; ct < 2; ++ct) {
            bf16x8 b = *reinterpret_cast<const bf16x8*>(&w3_f[((kc * 4 + wc * 2 + ct) * 64 + lane) * 8]);
            acc3[0][ct] = __builtin_amdgcn_mfma_f32_16x16x32_bf16(a0, b, acc3[0][ct], 0, 0, 0);
            acc3[1][ct] = __builtin_amdgcn_mfma_f32_16x16x32_bf16(a1, b, acc3[1][ct], 0, 0, 0);
        }
    }
    __syncthreads();                                          // B5
#pragma unroll
    for (int rt = 0; rt < 2; ++rt)
#pragma unroll
        for (int ct = 0; ct < 2; ++ct) {
            int o = wc * 32 + ct * 16 + l15;
            float bb = b3[o];
#pragma unroll
            for (int r = 0; r < 4; ++r) {
                int m = arow0 + rt * 16 + quad * 4 + r;
                smA[m * S3 + o] = f2bf(fmaxf(acc3[rt][ct][r] + bb, 0.f));
            }
        }
    __syncthreads();                                          // B6

    // ======== GEMM4 + head ========
    f32x4 acc4[2] = {};
#pragma unroll
    for (int kc = 0; kc < 2; ++kc) {
        bf16x8 a0 = *reinterpret_cast<const bf16x8*>(&smA[(arow0      + l15) * S3 + kc * 32 + quad * 8]);
        bf16x8 a1 = *reinterpret_cast<const bf16x8*>(&smA[(arow0 + 16 + l15) * S3 + kc * 32 + quad * 8]);
        bf16x8 b = *reinterpret_cast<const bf16x8*>(&w4_f[((kc * 2 + wc) * 64 + lane) * 8]);
        acc4[0] = __builtin_amdgcn_mfma_f32_16x16x32_bf16(a0, b, acc4[0], 0, 0, 0);
        acc4[1] = __builtin_amdgcn_mfma_f32_16x16x32_bf16(a1, b, acc4[1], 0, 0, 0);
    }
    {
        int o = wc * 16 + l15;
        float bb = b4[o], wv = w5[o];
        float part[2][4];
#pragma unroll
        for (int rt = 0; rt < 2; ++rt)
#pragma unroll
            for (int r = 0; r < 4; ++r)
                part[rt][r] = fmaxf(acc4[rt][r] + bb, 0.f) * wv;
#pragma unroll
        for (int mask = 1; mask < 16; mask <<= 1)
#pragma unroll
            for (int rt = 0; rt < 2; ++rt)
#pragma unroll
                for (int r = 0; r < 4; ++r)
                    part[rt][r] += __shfl_xor(part[rt][r], mask, 64);
        if (l15 == 0)
#pragma unroll
            for (int rt = 0; rt < 2; ++rt)
#pragma unroll
                for (int r = 0; r < 4; ++r) {
                    int m = arow0 + rt * 16 + quad * 4 + r;
                    s_l5[m][wc] = part[rt][r];
                }
    }
    __syncthreads();                                          // B7
    if (tid < 128) {
        int j = j0 + tid;
        float v = s_l5[tid][0] + s_l5[tid][1] + b5[0];
        out[i * 768 + j] = (j == i) ? -1.0e9f : v;
    }
}

// ---------------------------------------------------------------------------
extern "C" void kernel_launch(void* const* d_in, const int* in_sizes, int n_in,
                              void* d_out, int out_size, void* d_ws, size_t ws_size,
                              hipStream_t stream)
{
    const float* features   = (const float*)d_in[0];
    const float* boxes      = (const float*)d_in[1];
    const float* in_proj_w  = (const float*)d_in[2];
    const float* in_proj_b  = (const float*)d_in[3];
    const float* out_proj_w = (const float*)d_in[4];
    const float* out_proj_b = (const float*)d_in[5];
    const float* w1  = (const float*)d_in[6];
    const float* b1  = (const float*)d_in[7];
    const float* ln_g = (const float*)d_in[8];
    const float* ln_b = (const float*)d_in[9];
    const float* w2  = (const float*)d_in[10];
    const float* b2  = (const float*)d_in[11];
    const float* w3  = (const float*)d_in[12];
    const float* b3  = (const float*)d_in[13];
    const float* w4  = (const float*)d_in[14];
    const float* b4  = (const float*)d_in[15];
    const float* w5  = (const float*)d_in[16];
    const float* b5  = (const float*)d_in[17];
    float* out = (float*)d_out;

    // ---- workspace layout ----
    char* p = (char*)d_ws;
    unsigned short* qkvb = (unsigned short*)p; p += 768 * 768 * 2;
    unsigned short* Vt   = (unsigned short*)p; p += 256 * 768 * 2;
    unsigned short* Obf  = (unsigned short*)p; p += 768 * 256 * 2;
    unsigned short* attb = (unsigned short*)p; p += 768 * 256 * 2;
    float* att  = (float*)p; p += 768 * 256 * 4;
    float* AB   = (float*)p; p += 768 * 512 * 4;
    unsigned short* featb = (unsigned short*)p; p += 196608 * 2;
    unsigned short* inWb  = (unsigned short*)p; p += 196608 * 2;
    unsigned short* outWb = (unsigned short*)p; p += 65536 * 2;
    unsigned short* wABb  = (unsigned short*)p; p += 131072 * 2;
    unsigned short* w1c_f = (unsigned short*)p; p += 65536 * 2;
    unsigned short* w2g_f = (unsigned short*)p; p += 32768 * 2;
    unsigned short* w3_f  = (unsigned short*)p; p += 8192 * 2;
    unsigned short* w4_f  = (unsigned short*)p; p += 2048 * 2;
    float* biasAB = (float*)p; p += 512 * 4;
    float* w1s_p  = (float*)p; p += 768 * 4;
    float* c1v    = (float*)p; p += 128 * 4;
    float* c2v    = (float*)p; p += 128 * 4;

    pack_all<<<dim3(2734), dim3(256), 0, stream>>>(features, in_proj_w,
        out_proj_w, w1, w2, w3, w4, b1, ln_g, ln_b, b2,
        featb, inWb, outWb, wABb, w1c_f, w2g_f, w3_f, w4_f,
        biasAB, w1s_p, c1v, c2v);
    // qkv: Q,K rows -> qkvb; V columns transposed -> Vt
    gemm_bf<<<dim3(12, 12), dim3(256), 0, stream>>>(featb, inWb, in_proj_b,
        (float*)nullptr, qkvb, Vt, 768, 256);
    attn_mfma<<<dim3(8, 12), dim3(256), 0, stream>>>(qkvb, Vt, Obf);
    // att = O @ out_proj^T + b  (fp32 + bf16)
    gemm_bf<<<dim3(12, 4), dim3(256), 0, stream>>>(Obf, outWb, out_proj_b,
        att, attb, (unsigned short*)nullptr, 256, 256);
    // AB = att @ [w1a;w1b]^T + [b1;0]
    gemm_bf<<<dim3(12, 8), dim3(256), 0, stream>>>(attb, wABb, biasAB,
        AB, (unsigned short*)nullptr, (unsigned short*)nullptr, 512, 256);
    pair_mlp<<<dim3(768, 6), dim3(512), 0, stream>>>(att, attb, AB,
        w1c_f, w2g_f, w3_f, w4_f, w1s_p, boxes, c1v, c2v,
        b3, b4, w5, b5, out);
}